// Round 1
// baseline (336.047 us; speedup 1.0000x reference)
//
#include <hip/hip_runtime.h>
#include <hip/hip_bf16.h>

#define B_ 4
#define S_ 2048
#define H_ 1024
#define NH_ 16
#define DH_ 64
#define M_ (B_*S_)   // 8192

typedef __bf16 bf16x8 __attribute__((ext_vector_type(8)));
typedef float f32x4 __attribute__((ext_vector_type(4)));

static_assert(sizeof(__bf16) == 2, "bf16 size");

// ---------------------------------------------------------------- cast ----
__global__ __launch_bounds__(256)
void cast_f32_bf16(const float* __restrict__ src, __bf16* __restrict__ dst, int n)
{
    int i = (blockIdx.x * 256 + threadIdx.x) * 8;
    if (i < n) {
        float4 a = *(const float4*)(src + i);
        float4 b = *(const float4*)(src + i + 4);
        bf16x8 o;
        o[0] = (__bf16)a.x; o[1] = (__bf16)a.y; o[2] = (__bf16)a.z; o[3] = (__bf16)a.w;
        o[4] = (__bf16)b.x; o[5] = (__bf16)b.y; o[6] = (__bf16)b.z; o[7] = (__bf16)b.w;
        *(bf16x8*)(dst + i) = o;
    }
}

// ---------------------------------------------------------------- GEMM ----
// C[M,N] = A[M,K] @ Bw[N,K]^T + bias  (torch Linear). bf16 in, fp32 acc.
// EPI 0: write bf16 C.  EPI 1: write fp32 C + resid (residual add).
template<int EPI>
__global__ __launch_bounds__(256)
void gemm_bt(const __bf16* __restrict__ A, const __bf16* __restrict__ Bw,
             const float* __restrict__ bias, const float* __restrict__ resid,
             void* __restrict__ outp, int Mdim, int Ndim, int Kdim)
{
    __shared__ __align__(16) __bf16 As[128][72];
    __shared__ __align__(16) __bf16 Bs[128][72];

    const int tid  = threadIdx.x;
    const int lane = tid & 63, wv = tid >> 6;
    const int wr = wv >> 1, wc = wv & 1;           // 2x2 wave grid, 64x64 each
    const int m0 = blockIdx.y * 128, n0 = blockIdx.x * 128;
    const int rl = lane & 15, rg = lane >> 4;

    f32x4 acc[4][4] = {};

    const int sr = tid >> 3;            // staging row (0..31), 4 passes
    const int sc = (tid & 7) * 8;       // staging col (bf16 elements)

    for (int k0 = 0; k0 < Kdim; k0 += 64) {
#pragma unroll
        for (int p = 0; p < 4; ++p) {
            int r = sr + p * 32;
            *(bf16x8*)(&As[r][sc]) = *(const bf16x8*)(A  + (size_t)(m0 + r) * Kdim + k0 + sc);
            *(bf16x8*)(&Bs[r][sc]) = *(const bf16x8*)(Bw + (size_t)(n0 + r) * Kdim + k0 + sc);
        }
        __syncthreads();
#pragma unroll
        for (int ks = 0; ks < 2; ++ks) {
            const int kb = ks * 32 + rg * 8;       // element offset in LDS row
            bf16x8 af[4], bfr[4];
#pragma unroll
            for (int m = 0; m < 4; ++m) af[m]  = *(const bf16x8*)(&As[wr * 64 + m * 16 + rl][kb]);
#pragma unroll
            for (int n = 0; n < 4; ++n) bfr[n] = *(const bf16x8*)(&Bs[wc * 64 + n * 16 + rl][kb]);
#pragma unroll
            for (int m = 0; m < 4; ++m)
#pragma unroll
                for (int n = 0; n < 4; ++n)
                    acc[m][n] = __builtin_amdgcn_mfma_f32_16x16x32_bf16(af[m], bfr[n], acc[m][n], 0, 0, 0);
        }
        __syncthreads();
    }

    // epilogue: C/D layout col = lane&15, row = (lane>>4)*4 + reg   [m89]
#pragma unroll
    for (int m = 0; m < 4; ++m) {
#pragma unroll
        for (int n = 0; n < 4; ++n) {
            const int col = n0 + wc * 64 + n * 16 + rl;
            const float bv = bias[col];
#pragma unroll
            for (int r = 0; r < 4; ++r) {
                const int row = m0 + wr * 64 + m * 16 + rg * 4 + r;
                const size_t idx = (size_t)row * Ndim + col;
                float v = acc[m][n][r] + bv;
                if (EPI == 0) {
                    ((__bf16*)outp)[idx] = (__bf16)v;
                } else {
                    ((float*)outp)[idx] = v + resid[idx];
                }
            }
        }
    }
}

// ---------------------------------------------------------- V transpose ----
// v [B,S,H] bf16 -> vt [B,NH,DH,S] bf16
__global__ __launch_bounds__(256)
void transpose_v(const __bf16* __restrict__ v, __bf16* __restrict__ vt)
{
    __shared__ __align__(16) __bf16 T[64][72];
    const int s0 = blockIdx.x * 64;
    const int bh = blockIdx.y;
    const int b = bh / NH_, h = bh % NH_;
    const int tid = threadIdx.x;
    const int r  = tid >> 2;            // 0..63
    const int c  = (tid & 3) * 16;      // 0,16,32,48

#pragma unroll
    for (int i = 0; i < 2; ++i)
        *(bf16x8*)(&T[r][c + i * 8]) =
            *(const bf16x8*)(v + (size_t)(b * S_ + s0 + r) * H_ + h * DH_ + c + i * 8);
    __syncthreads();

    // thread (r=d, c=s-block): write vt row d, 16 s values
    bf16x8 o0, o1;
#pragma unroll
    for (int i = 0; i < 8; ++i) { o0[i] = T[c + i][r]; o1[i] = T[c + 8 + i][r]; }
    size_t obase = ((size_t)(b * NH_ + h) * DH_ + r) * S_ + s0 + c;
    *(bf16x8*)(vt + obase)     = o0;
    *(bf16x8*)(vt + obase + 8) = o1;
}

// ------------------------------------------------------------ attention ----
// grid (S/128, NH, B); 256 thr = 4 waves, wave w owns q-rows [w*32, w*32+32)
__global__ __launch_bounds__(256)
void attn_fwd(const __bf16* __restrict__ q, const __bf16* __restrict__ k,
              const __bf16* __restrict__ vt, const float* __restrict__ mask,
              __bf16* __restrict__ ctx)
{
    __shared__ __align__(16) __bf16 Ks[128][72];    // keys x DH
    __shared__ __align__(16) __bf16 Vs[64][136];    // DH x keys (V^T)
    __shared__ __align__(16) __bf16 Ps[128][136];   // probs (wave-private rows)
    __shared__ float Ms[128];

    const int qt0 = blockIdx.x * 128;
    const int h = blockIdx.y, b = blockIdx.z;
    const int tid = threadIdx.x, lane = tid & 63, wv = tid >> 6;
    const int rl = lane & 15, rg = lane >> 4;

    // Q fragments, held in registers for the whole kernel
    bf16x8 qf[2][2];
#pragma unroll
    for (int m = 0; m < 2; ++m)
#pragma unroll
        for (int ks = 0; ks < 2; ++ks) {
            int row = b * S_ + qt0 + wv * 32 + m * 16 + rl;
            int col = h * DH_ + ks * 32 + rg * 8;
            qf[m][ks] = *(const bf16x8*)(q + (size_t)row * H_ + col);
        }

    f32x4 cacc[2][4] = {};
    float mrow[2][4], lrow[2][4];
#pragma unroll
    for (int m = 0; m < 2; ++m)
#pragma unroll
        for (int r = 0; r < 4; ++r) { mrow[m][r] = -1e30f; lrow[m][r] = 0.f; }

    const int sKr = tid >> 3, sKc = (tid & 7) * 8;
    const int sVr = tid >> 4, sVc = (tid & 15) * 8;

    for (int kt = 0; kt < S_; kt += 128) {
        // ---- stage K tile (128 keys x 64), V^T tile (64 x 128 keys), mask
#pragma unroll
        for (int p = 0; p < 4; ++p) {
            int r = sKr + p * 32;
            *(bf16x8*)(&Ks[r][sKc]) =
                *(const bf16x8*)(k + (size_t)(b * S_ + kt + r) * H_ + h * DH_ + sKc);
        }
#pragma unroll
        for (int p = 0; p < 4; ++p) {
            int r = sVr + p * 16;
            *(bf16x8*)(&Vs[r][sVc]) =
                *(const bf16x8*)(vt + ((size_t)(b * NH_ + h) * DH_ + r) * S_ + kt + sVc);
        }
        if (tid < 128) Ms[tid] = mask[b * S_ + kt + tid];
        __syncthreads();

        // ---- scores = Q @ K^T : wave computes 32 rows x 128 keys
        f32x4 sacc[2][8] = {};
#pragma unroll
        for (int ks = 0; ks < 2; ++ks) {
            const int kb = ks * 32 + rg * 8;
            bf16x8 kf[8];
#pragma unroll
            for (int n = 0; n < 8; ++n) kf[n] = *(const bf16x8*)(&Ks[n * 16 + rl][kb]);
#pragma unroll
            for (int m = 0; m < 2; ++m)
#pragma unroll
                for (int n = 0; n < 8; ++n)
                    sacc[m][n] = __builtin_amdgcn_mfma_f32_16x16x32_bf16(qf[m][ks], kf[n], sacc[m][n], 0, 0, 0);
        }

        // ---- online softmax (rows are wave-local; 16-lane shfl reduce)
        float mk[8];
#pragma unroll
        for (int n = 0; n < 8; ++n) mk[n] = Ms[n * 16 + rl];
#pragma unroll
        for (int m = 0; m < 2; ++m) {
#pragma unroll
            for (int r = 0; r < 4; ++r) {
                float mx = -1e30f;
#pragma unroll
                for (int n = 0; n < 8; ++n) {
                    float s = sacc[m][n][r] * 0.125f + mk[n];
                    sacc[m][n][r] = s;
                    mx = fmaxf(mx, s);
                }
                mx = fmaxf(mx, __shfl_xor(mx, 1, 16));
                mx = fmaxf(mx, __shfl_xor(mx, 2, 16));
                mx = fmaxf(mx, __shfl_xor(mx, 4, 16));
                mx = fmaxf(mx, __shfl_xor(mx, 8, 16));
                float mnew = fmaxf(mrow[m][r], mx);
                float ef = __expf(mrow[m][r] - mnew);
                mrow[m][r] = mnew;
                float rs = 0.f;
#pragma unroll
                for (int n = 0; n < 8; ++n) {
                    float p = __expf(sacc[m][n][r] - mnew);
                    sacc[m][n][r] = p;
                    rs += p;
                }
                rs += __shfl_xor(rs, 1, 16);
                rs += __shfl_xor(rs, 2, 16);
                rs += __shfl_xor(rs, 4, 16);
                rs += __shfl_xor(rs, 8, 16);
                lrow[m][r] = lrow[m][r] * ef + rs;
#pragma unroll
                for (int n = 0; n < 4; ++n) cacc[m][n][r] *= ef;
            }
        }

        // ---- P -> LDS (reshape col-slice acc into row-contiguous A frags)
#pragma unroll
        for (int m = 0; m < 2; ++m)
#pragma unroll
            for (int n = 0; n < 8; ++n)
#pragma unroll
                for (int r = 0; r < 4; ++r)
                    Ps[wv * 32 + m * 16 + rg * 4 + r][n * 16 + rl] = (__bf16)sacc[m][n][r];
        __syncthreads();

        // ---- ctx += P @ V  (V^T rows are d, k-contiguous keys)
#pragma unroll
        for (int ks2 = 0; ks2 < 4; ++ks2) {
            const int kb = ks2 * 32 + rg * 8;
            bf16x8 vb[4];
#pragma unroll
            for (int n = 0; n < 4; ++n) vb[n] = *(const bf16x8*)(&Vs[n * 16 + rl][kb]);
#pragma unroll
            for (int m = 0; m < 2; ++m) {
                bf16x8 pa = *(const bf16x8*)(&Ps[wv * 32 + m * 16 + rl][kb]);
#pragma unroll
                for (int n = 0; n < 4; ++n)
                    cacc[m][n] = __builtin_amdgcn_mfma_f32_16x16x32_bf16(pa, vb[n], cacc[m][n], 0, 0, 0);
            }
        }
        __syncthreads();   // protect Ks/Vs before next staging
    }

    // ---- normalize + write ctx [B,S,H] bf16
#pragma unroll
    for (int m = 0; m < 2; ++m) {
#pragma unroll
        for (int r = 0; r < 4; ++r) {
            float inv = 1.f / lrow[m][r];
            int srow = qt0 + wv * 32 + m * 16 + rg * 4 + r;
            size_t gbase = (size_t)(b * S_ + srow) * H_ + h * DH_;
#pragma unroll
            for (int n = 0; n < 4; ++n)
                ctx[gbase + n * 16 + rl] = (__bf16)(cacc[m][n][r] * inv);
        }
    }
}

// ------------------------------------------------------------ layernorm ----
__global__ __launch_bounds__(256)
void ln_kernel(const float* __restrict__ x, const float* __restrict__ gamma,
               const float* __restrict__ beta, float* __restrict__ out)
{
    const int row = blockIdx.x;
    const int t = threadIdx.x;
    const float* xr = x + (size_t)row * H_;
    float4 v = *(const float4*)(xr + t * 4);
    float s  = v.x + v.y + v.z + v.w;
    float ss = v.x * v.x + v.y * v.y + v.z * v.z + v.w * v.w;
#pragma unroll
    for (int off = 1; off < 64; off <<= 1) {
        s  += __shfl_xor(s, off, 64);
        ss += __shfl_xor(ss, off, 64);
    }
    __shared__ float sb[8];
    const int wv = t >> 6, lane = t & 63;
    if (lane == 0) { sb[wv] = s; sb[4 + wv] = ss; }
    __syncthreads();
    s  = sb[0] + sb[1] + sb[2] + sb[3];
    ss = sb[4] + sb[5] + sb[6] + sb[7];
    const float mu = s * (1.f / H_);
    const float var = ss * (1.f / H_) - mu * mu;
    const float rstd = rsqrtf(var + 1e-12f);
    float4 g = *(const float4*)(gamma + t * 4);
    float4 bt = *(const float4*)(beta + t * 4);
    float4 o;
    o.x = (v.x - mu) * rstd * g.x + bt.x;
    o.y = (v.y - mu) * rstd * g.y + bt.y;
    o.z = (v.z - mu) * rstd * g.z + bt.z;
    o.w = (v.w - mu) * rstd * g.w + bt.w;
    *(float4*)(out + (size_t)row * H_ + t * 4) = o;
}

// -------------------------------------------------------------- launch ----
extern "C" void kernel_launch(void* const* d_in, const int* in_sizes, int n_in,
                              void* d_out, int out_size, void* d_ws, size_t ws_size,
                              hipStream_t stream)
{
    const float* hs    = (const float*)d_in[0];
    const float* mask  = (const float*)d_in[1];
    const float* Wq    = (const float*)d_in[2];
    const float* bq    = (const float*)d_in[3];
    const float* Wk    = (const float*)d_in[4];
    const float* bk    = (const float*)d_in[5];
    const float* Wv    = (const float*)d_in[6];
    const float* bv    = (const float*)d_in[7];
    const float* Wo    = (const float*)d_in[8];
    const float* bo    = (const float*)d_in[9];
    const float* gamma = (const float*)d_in[10];
    const float* beta  = (const float*)d_in[11];

    char* ws = (char*)d_ws;
    const size_t MB = 1ull << 20;
    __bf16* x_bf   = (__bf16*)(ws);             // 16 MB (dead after QKV GEMMs)
    __bf16* wq_bf  = (__bf16*)(ws + 16 * MB);   // 2 MB each
    __bf16* wk_bf  = (__bf16*)(ws + 18 * MB);
    __bf16* wv_bf  = (__bf16*)(ws + 20 * MB);
    __bf16* wo_bf  = (__bf16*)(ws + 22 * MB);
    __bf16* q_bf   = (__bf16*)(ws + 24 * MB);   // 16 MB
    __bf16* k_bf   = (__bf16*)(ws + 40 * MB);   // 16 MB
    __bf16* v_bf   = (__bf16*)(ws + 56 * MB);   // 16 MB
    __bf16* vt_bf  = (__bf16*)(ws + 72 * MB);   // 16 MB   (total 88 MB)
    __bf16* ctx_bf = (__bf16*)(ws);             // aliases x_bf (x dead by then)
    float*  pre    = (float*)(ws + 24 * MB);    // 32 MB, aliases q/k (dead by then)

    const int nx = M_ * H_;
    const int nw = H_ * H_;
    cast_f32_bf16<<<nx / 2048, 256, 0, stream>>>(hs, x_bf, nx);
    cast_f32_bf16<<<nw / 2048, 256, 0, stream>>>(Wq, wq_bf, nw);
    cast_f32_bf16<<<nw / 2048, 256, 0, stream>>>(Wk, wk_bf, nw);
    cast_f32_bf16<<<nw / 2048, 256, 0, stream>>>(Wv, wv_bf, nw);
    cast_f32_bf16<<<nw / 2048, 256, 0, stream>>>(Wo, wo_bf, nw);

    dim3 gg(H_ / 128, M_ / 128);
    gemm_bt<0><<<gg, 256, 0, stream>>>(x_bf, wq_bf, bq, nullptr, q_bf, M_, H_, H_);
    gemm_bt<0><<<gg, 256, 0, stream>>>(x_bf, wk_bf, bk, nullptr, k_bf, M_, H_, H_);
    gemm_bt<0><<<gg, 256, 0, stream>>>(x_bf, wv_bf, bv, nullptr, v_bf, M_, H_, H_);

    transpose_v<<<dim3(S_ / 64, B_ * NH_), 256, 0, stream>>>(v_bf, vt_bf);

    attn_fwd<<<dim3(S_ / 128, NH_, B_), 256, 0, stream>>>(q_bf, k_bf, vt_bf, mask, ctx_bf);

    gemm_bt<1><<<gg, 256, 0, stream>>>(ctx_bf, wo_bf, bo, hs, pre, M_, H_, H_);

    ln_kernel<<<M_, 256, 0, stream>>>(pre, gamma, beta, (float*)d_out);
}